// Round 2
// baseline (254.727 us; speedup 1.0000x reference)
//
#include <hip/hip_runtime.h>
#include <stdint.h>

// SFFM — inputs [L=4,B=8,C=256,H=64,W=64] float32 (bf16-precision values),
// W [256,256] float32.
//   gap    = mean(inputs, axis=(3,4))             -> [L,B,C]
//   scores = gap @ W^T                            -> [L,B,C]
//   attn   = softmax over L                       -> [L,B,C]
//   out    = inputs * attn[:,:,:,None,None]       (float32 out)
//
// Memory-bound: 128 MiB in (read twice) + 128 MiB out. 3-kernel split.

#define L_DIM 4
#define B_DIM 8
#define C_DIM 256
#define HW    4096                      // 64*64 elements per (l,b,c) channel
#define F4_PER_CH (HW / 4)              // 1024 float4 per channel
#define NCH   (L_DIM * B_DIM * C_DIM)   // 8192 channels
#define NF4   ((size_t)NCH * F4_PER_CH) // 8,388,608 float4 packs

// ---- Kernel 1: GAP. One block (256 threads) per (l,b,c) channel. ----
__global__ __launch_bounds__(256) void gap_kernel(
        const float4* __restrict__ in, float* __restrict__ gap) {
    const int ch = blockIdx.x;                       // 0..8191
    const float4* base = in + (size_t)ch * F4_PER_CH;
    float s = 0.0f;
    // 1024 packs / 256 threads = 4 packs per thread, coalesced 16B/lane
    #pragma unroll
    for (int k = 0; k < 4; ++k) {
        float4 p = base[threadIdx.x + k * 256];
        s += (p.x + p.y) + (p.z + p.w);
    }
    // wave-64 shuffle reduce
    #pragma unroll
    for (int off = 32; off > 0; off >>= 1)
        s += __shfl_down(s, off, 64);
    __shared__ float wsum[4];
    const int wave = threadIdx.x >> 6;
    const int lane = threadIdx.x & 63;
    if (lane == 0) wsum[wave] = s;
    __syncthreads();
    if (threadIdx.x == 0) {
        float t = wsum[0] + wsum[1] + wsum[2] + wsum[3];
        gap[ch] = t * (1.0f / (float)HW);
    }
}

// ---- Kernel 2: linear + softmax over L. One block per b (8 blocks). ----
// Thread d (0..255) computes scores[l,b,d] for all 4 l's, then softmax over l.
__global__ __launch_bounds__(256) void attn_kernel(
        const float* __restrict__ gap, const float* __restrict__ Wf,
        float* __restrict__ attn) {
    const int b = blockIdx.x;     // 0..7
    const int d = threadIdx.x;    // 0..255
    __shared__ float g[L_DIM][C_DIM];
    #pragma unroll
    for (int l = 0; l < L_DIM; ++l)
        g[l][d] = gap[(l * B_DIM + b) * C_DIM + d];
    __syncthreads();

    float acc[L_DIM] = {0.f, 0.f, 0.f, 0.f};
    const float* wrow = Wf + (size_t)d * C_DIM;   // row d of W (y = x @ W^T)
    #pragma unroll 4
    for (int c = 0; c < C_DIM; ++c) {
        float w = wrow[c];
        #pragma unroll
        for (int l = 0; l < L_DIM; ++l)
            acc[l] += g[l][c] * w;                // LDS broadcast reads
    }
    float m = fmaxf(fmaxf(acc[0], acc[1]), fmaxf(acc[2], acc[3]));
    float e[L_DIM], se = 0.f;
    #pragma unroll
    for (int l = 0; l < L_DIM; ++l) { e[l] = __expf(acc[l] - m); se += e[l]; }
    float inv = 1.0f / se;
    #pragma unroll
    for (int l = 0; l < L_DIM; ++l)
        attn[(l * B_DIM + b) * C_DIM + d] = e[l] * inv;
}

// ---- Kernel 3: out = in * attn (broadcast per channel). ----
__global__ __launch_bounds__(256) void scale_kernel(
        const float4* __restrict__ in, const float* __restrict__ attn,
        float4* __restrict__ out) {
    const size_t i = (size_t)blockIdx.x * 256 + threadIdx.x;  // float4 index
    float a = attn[i >> 10];                 // 1024 float4 per channel
    float4 p = in[i];
    float4 q;
    q.x = p.x * a;
    q.y = p.y * a;
    q.z = p.z * a;
    q.w = p.w * a;
    out[i] = q;
}

extern "C" void kernel_launch(void* const* d_in, const int* in_sizes, int n_in,
                              void* d_out, int out_size, void* d_ws, size_t ws_size,
                              hipStream_t stream) {
    const float4* in_p  = (const float4*)d_in[0];
    const float*  W_p   = (const float*)d_in[1];
    float4*       out_p = (float4*)d_out;

    float* gap  = (float*)d_ws;                 // 8192 floats
    float* attn = gap + NCH;                    // 8192 floats

    gap_kernel<<<NCH, 256, 0, stream>>>(in_p, gap);
    attn_kernel<<<B_DIM, 256, 0, stream>>>(gap, W_p, attn);
    scale_kernel<<<(int)(NF4 / 256), 256, 0, stream>>>(in_p, attn, out_p);
}

// Round 3
// 244.086 us; speedup vs baseline: 1.0436x; 1.0436x over previous
//
#include <hip/hip_runtime.h>
#include <stdint.h>

// SFFM — inputs [L=4,B=8,C=256,H=64,W=64] float32, W [256,256] float32.
//   gap    = mean(inputs, axis=(3,4))             -> [L,B,C]
//   scores = gap @ W^T                            -> [L,B,C]
//   attn   = softmax over L                       -> [L,B,C]
//   out    = inputs * attn[:,:,:,None,None]
//
// 2-kernel structure:
//   K1: GAP (one block per channel, coalesced float4 reads)
//   K2: fused attn+scale — each block recomputes its channel's attention
//       (4 dots of 256, coalesced W-row read) then streams scale.

#define L_DIM 4
#define B_DIM 8
#define C_DIM 256
#define HW    4096                      // 64*64 per (l,b,c) channel
#define F4_PER_CH (HW / 4)              // 1024 float4 per channel
#define NCH   (L_DIM * B_DIM * C_DIM)   // 8192 channels

// ---- Kernel 1: GAP. One block (256 threads) per channel. ----
__global__ __launch_bounds__(256) void gap_kernel(
        const float4* __restrict__ in, float* __restrict__ gap) {
    const int ch = blockIdx.x;
    const float4* base = in + (size_t)ch * F4_PER_CH;
    float s = 0.0f;
    #pragma unroll
    for (int k = 0; k < 4; ++k) {
        float4 p = base[threadIdx.x + k * 256];
        s += (p.x + p.y) + (p.z + p.w);
    }
    #pragma unroll
    for (int off = 32; off > 0; off >>= 1)
        s += __shfl_down(s, off, 64);
    __shared__ float wsum[4];
    const int wave = threadIdx.x >> 6;
    const int lane = threadIdx.x & 63;
    if (lane == 0) wsum[wave] = s;
    __syncthreads();
    if (threadIdx.x == 0) {
        gap[ch] = (wsum[0] + wsum[1] + wsum[2] + wsum[3]) * (1.0f / (float)HW);
    }
}

// ---- Kernel 2: fused attention + scale. One block per channel. ----
// Channel ch = (l*B + b)*C + d. Block computes scores[l',b,d] for l'=0..3
// (thread c holds W[d,c] — coalesced), softmaxes over l', picks its own l,
// then scales its 16 KiB of input.
__global__ __launch_bounds__(256) void attn_scale_kernel(
        const float4* __restrict__ in, const float* __restrict__ gap,
        const float* __restrict__ Wf, float4* __restrict__ out) {
    const int ch = blockIdx.x;
    const int d  = ch & (C_DIM - 1);
    const int lb = ch >> 8;              // l*B + b
    const int b  = lb & (B_DIM - 1);
    const int l  = lb >> 3;
    const int c  = threadIdx.x;

    // per-thread products for all 4 layers
    const float w = Wf[(size_t)d * C_DIM + c];          // coalesced row read
    float p0 = gap[(0 * B_DIM + b) * C_DIM + c] * w;
    float p1 = gap[(1 * B_DIM + b) * C_DIM + c] * w;
    float p2 = gap[(2 * B_DIM + b) * C_DIM + c] * w;
    float p3 = gap[(3 * B_DIM + b) * C_DIM + c] * w;

    // wave-64 shuffle reduce (4 values)
    #pragma unroll
    for (int off = 32; off > 0; off >>= 1) {
        p0 += __shfl_down(p0, off, 64);
        p1 += __shfl_down(p1, off, 64);
        p2 += __shfl_down(p2, off, 64);
        p3 += __shfl_down(p3, off, 64);
    }
    __shared__ float part[4][4];   // [wave][l']
    __shared__ float a_bcast;
    const int wave = threadIdx.x >> 6;
    const int lane = threadIdx.x & 63;
    if (lane == 0) {
        part[wave][0] = p0; part[wave][1] = p1;
        part[wave][2] = p2; part[wave][3] = p3;
    }
    __syncthreads();
    if (threadIdx.x == 0) {
        float s0 = part[0][0] + part[1][0] + part[2][0] + part[3][0];
        float s1 = part[0][1] + part[1][1] + part[2][1] + part[3][1];
        float s2 = part[0][2] + part[1][2] + part[2][2] + part[3][2];
        float s3 = part[0][3] + part[1][3] + part[2][3] + part[3][3];
        float m  = fmaxf(fmaxf(s0, s1), fmaxf(s2, s3));
        float e0 = __expf(s0 - m), e1 = __expf(s1 - m);
        float e2 = __expf(s2 - m), e3 = __expf(s3 - m);
        float el = (l == 0) ? e0 : (l == 1) ? e1 : (l == 2) ? e2 : e3;
        a_bcast = el / (e0 + e1 + e2 + e3);
    }
    __syncthreads();
    const float a = a_bcast;

    // stream-scale this channel: 1024 float4 / 256 threads = 4 iters
    const float4* src = in  + (size_t)ch * F4_PER_CH;
    float4*       dst = out + (size_t)ch * F4_PER_CH;
    #pragma unroll
    for (int k = 0; k < 4; ++k) {
        float4 p = src[threadIdx.x + k * 256];
        float4 q;
        q.x = p.x * a; q.y = p.y * a; q.z = p.z * a; q.w = p.w * a;
        dst[threadIdx.x + k * 256] = q;
    }
}

extern "C" void kernel_launch(void* const* d_in, const int* in_sizes, int n_in,
                              void* d_out, int out_size, void* d_ws, size_t ws_size,
                              hipStream_t stream) {
    const float4* in_p  = (const float4*)d_in[0];
    const float*  W_p   = (const float*)d_in[1];
    float4*       out_p = (float4*)d_out;

    float* gap = (float*)d_ws;                  // 8192 floats

    gap_kernel<<<NCH, 256, 0, stream>>>(in_p, gap);
    attn_scale_kernel<<<NCH, 256, 0, stream>>>(in_p, gap, W_p, out_p);
}